// Round 15
// baseline (178.637 us; speedup 1.0000x reference)
//
#include <hip/hip_runtime.h>
#include <hip/hip_bf16.h>

#define DIM    286
#define DIMP   288
#define NBATCH 256
#define NB_    24
#define NA_    48
#define ZC     32        // z per tile
#define NTILES 1728      // 55296/32
#define NCHUNK 256       // k_main grid.x; 192 blocks x 7 tiles + 64 x 6
#define S_CONST 16.911534525287763f
#define INV_S   0.05913123959890826f
#define ACT_CST 1.5927f  // normalize2mom const for tanh
#define TWO_LOG2E 2.8853900817779268f   // 2*log2(e): expf(-2a) == exp2(-TWO_LOG2E*a)

typedef short bf16x8 __attribute__((ext_vector_type(8)));
typedef float f32x4  __attribute__((ext_vector_type(4)));

// ws layout (bytes) -- Fbf eliminated (fa built once from F in-register)
#define WS_PART 0u                            // part: 256*256*288*2 = 37748736

typedef const __attribute__((address_space(1))) char GA;
typedef __attribute__((address_space(3))) char LA;
__device__ __forceinline__ void gload_lds16(const void* g, void* l) {
    __builtin_amdgcn_global_load_lds((GA*)g, (LA*)l, 16, 0, 0);
}

// ---------- fused main, 1024 thr = 16 waves x M=16 rows = 256 rows, grid 256
// (1 block/CU, 124 KiB LDS).  KEY: at 16 waves the block runs 4 waves/SIMD ->
// per-wave register budget is 512 (not 256): acc shrinks to 72 AGPR and the fa
// A-frag cache (36 VGPR) is legal again -- built ONCE per kernel directly from
// F (bit-identical to prepF's bf16(INV_S*F)), so prepF+Fbf are deleted.
// Per tile: DMA raw f32 D -> Traw (dbuf, counted vmcnt) -> strength-reduced
// convert -> GEMM1 -> act -> GEMM2.  part layout byte-identical to R8
// (wave w == R8's (w>>1, h=w&1)), so k_reduce is unchanged.
__launch_bounds__(1024, 4)
__global__ void k_main(const float* __restrict__ F,
                       const float* __restrict__ D,
                       const float* __restrict__ qw,
                       __hip_bfloat16* __restrict__ part) {
    __shared__ __align__(16) float Traw[2][9216];  // raw f32 tile dbuf: 73728 B (DMA uses 36608/buf)
    __shared__ __align__(16) char DsB[18432];      // bf16 [ks][z][i32], hash ((z&7)<<4)
    __shared__ __align__(16) char DtB[18432];      // bf16 [i][z],      hash ((i&7)<<4)
    __shared__ __align__(16) char GsB[16384];      // per-wave 1KB G,   hash ((row>>2)<<4)
    float* qs = &Traw[0][9152];                    // 24 floats in Traw[0] slack (DMA-untouched)
    // total LDS = 73728+18432+18432+16384 = 126976 B

    int t = threadIdx.x;
    int wave = t >> 6, lane = t & 63, ln = lane & 15, q = lane >> 4;
    int cA = (ln * 64 + q * 16) ^ ((ln & 7) << 4);
    int gA = (wave << 10) + ((ln * 64 + q * 16) ^ ((ln >> 2) << 4));

    if (t < 24) qs[t] = qw[t] * S_CONST;

    // fa cache: wave's 16 rows x 9 K-steps, built once from F (f32, L2-resident).
    // bf16(F*INV_S) with RTNE == prepF's path.  Cols 286,287 are zero-pad;
    // OOB lanes (ks=8,q=3,jj>=6) are exec-masked on the load.
    bf16x8 fa[9];
    {
        const float* Fr = F + (size_t)(wave * 16 + ln) * DIM + q * 8;
        #pragma unroll
        for (int ks = 0; ks < 9; ++ks) {
            __hip_bfloat16 o[8];
            #pragma unroll
            for (int jj = 0; jj < 8; ++jj) {
                int col = q * 8 + ks * 32 + jj;
                float fv = 0.f;
                if (col < DIM) fv = Fr[ks * 32 + jj];
                o[jj] = __float2bfloat16(fv * INV_S);
            }
            fa[ks] = *(const bf16x8*)o;
        }
    }

    f32x4 acc[18];
    #pragma unroll
    for (int n = 0; n < 18; ++n) acc[n] = (f32x4){0.f, 0.f, 0.f, 0.f};

    int bx = blockIdx.x;
    int tstart = (bx < 192) ? bx * 7 : bx * 6 + 192;   // 192*7 + 64*6 = 1728
    int ntile = (bx < 192) ? 7 : 6;

    // seed for the strength-reduced d -> (z, i2) walk (one div/mod total)
    int zseed = t / 144, iseed = t % 144;

    // DMA one raw f32 tile (36608 B = 35 full 1KB chunks + 768B tail):
    // 16 waves: waves 0-3 issue 3 chunks, waves 4-15 issue 2
    #define STAGE(TI, BUF) do {                                                    \
        const char* _s = (const char*)(D + (size_t)(tstart + (TI)) * 9152);        \
        char* _d = (char*)Traw[BUF];                                               \
        _Pragma("unroll")                                                          \
        for (int _j = 0; _j < 3; ++_j) {                                           \
            int _c = wave + _j * 16;                                               \
            if (_c < 35 || (_c == 35 && lane < 48))                                \
                gload_lds16(_s + _c * 1024 + lane * 16, _d + _c * 1024);           \
        }                                                                          \
    } while (0)

    // fa loads + qs store drained, then two tiles in flight
    asm volatile("s_waitcnt vmcnt(0) lgkmcnt(0)" ::: "memory");
    STAGE(0, 0);
    STAGE(1, 1);   // ntile >= 6 always

    #pragma unroll 1
    for (int k = 0; k < ntile; ++k) {
        // (1) tile-k batch landed; leave tile-(k+1) batch in flight
        if (k + 1 < ntile) {
            if (wave < 4) asm volatile("s_waitcnt vmcnt(3)" ::: "memory");
            else          asm volatile("s_waitcnt vmcnt(2)" ::: "memory");
        } else {
            asm volatile("s_waitcnt vmcnt(0)" ::: "memory");
        }
        __builtin_amdgcn_s_barrier();

        // (2) convert Traw[k&1] -> DsB + DtB, division-free (1024 thr share).
        //     Ds: d = t + m*1024, m=0..3, + tail d=t+4096 for t<512.
        //     1024 = 7*144 + 16 -> walk zz+=7, ii+=16 (single wrap).
        const float* T = Traw[k & 1];
        {
            int zz = zseed, ii = iseed;
            #pragma unroll
            for (int m = 0; m < 5; ++m) {
                if (m < 4 || t < 512) {
                    int i = ii * 2;
                    __hip_bfloat162 o2;
                    if (i < DIM) {
                        float2 v = *(const float2*)(&T[zz * DIM + i]);   // 8B aligned
                        o2.x = __float2bfloat16(v.x); o2.y = __float2bfloat16(v.y);
                    } else {
                        o2.x = __float2bfloat16(0.f); o2.y = o2.x;       // pad 286..287
                    }
                    int off = (((i >> 5) * 2048) + zz * 64 + (i & 31) * 2) ^ ((zz & 7) << 4);
                    *(__hip_bfloat162*)(DsB + off) = o2;
                }
                zz += 7; ii += 16;
                if (ii >= 144) { ii -= 144; ++zz; }
            }
        }
        // Dt (PURE bf16 transpose; qw folded into act): tasks t and 1024+t(<128)
        {
            int i = t >> 2, zc = t & 3;            // i in [0,256)
            __hip_bfloat16 o8[8];
            #pragma unroll
            for (int j = 0; j < 8; ++j)
                o8[j] = __float2bfloat16(T[(zc * 8 + j) * DIM + i]);
            int off = (i * 64 + zc * 16) ^ ((i & 7) << 4);
            *(bf16x8*)(DtB + off) = *(const bf16x8*)o8;
        }
        if (t < 128) {
            int idx = 1024 + t;
            int i = idx >> 2, zc = idx & 3;        // i in [256,288)
            __hip_bfloat16 o8[8];
            #pragma unroll
            for (int j = 0; j < 8; ++j)
                o8[j] = __float2bfloat16(T[(zc * 8 + j) * DIM + i]);
            int off = (i * 64 + zc * 16) ^ ((i & 7) << 4);
            *(bf16x8*)(DtB + off) = *(const bf16x8*)o8;
        }
        asm volatile("s_waitcnt lgkmcnt(0)" ::: "memory");
        __builtin_amdgcn_s_barrier();

        // (3) issue tile k+2 DMA into the Traw buffer convert just finished reading
        if (k + 2 < ntile) STAGE(k + 2, k & 1);

        // per-lane quadrature scale: qv(z) = qs[(z/48)%24], z = z0t + zh*16 + ln
        int z0t = (tstart + k) * 32;
        float qv0 = qs[((z0t + ln) / 48) % 24];
        float qv1 = qs[((z0t + 16 + ln) / 48) % 24];

        // (4) GEMM1: G[16 x 32] per wave, K=288; A from registers, B swizzled LDS
        f32x4 g0 = (f32x4){0.f,0.f,0.f,0.f}, g1 = (f32x4){0.f,0.f,0.f,0.f};
        #pragma unroll
        for (int ks = 0; ks < 9; ++ks) {
            bf16x8 b0 = *(const bf16x8*)(DsB + ks * 2048 + cA);
            bf16x8 b1 = *(const bf16x8*)(DsB + ks * 2048 + 1024 + cA);
            g0 = __builtin_amdgcn_mfma_f32_16x16x32_bf16(fa[ks], b0, g0, 0, 0, 0);
            g1 = __builtin_amdgcn_mfma_f32_16x16x32_bf16(fa[ks], b1, g1, 0, 0, 0);
        }
        // act = qv * ACT_CST*tanh(g): tanh(a) = 1 - 2e/(1+e), e = 2^(-2*log2e*a)
        #pragma unroll
        for (int zh = 0; zh < 2; ++zh) {
            f32x4 g = (zh == 0) ? g0 : g1;
            float qv = (zh == 0) ? qv0 : qv1;
            #pragma unroll
            for (int r = 0; r < 4; ++r) {
                float x = g[r];
                float a = fabsf(x);
                float e = __builtin_amdgcn_exp2f(-TWO_LOG2E * a);
                float v = ACT_CST - 2.f * ACT_CST * e * __builtin_amdgcn_rcpf(1.f + e);
                v = copysignf(v, x) * qv;
                int row = q * 4 + r;                         // row>>2 = q
                int goff = (wave << 10)
                         + ((row * 64 + (zh * 16 + ln) * 2) ^ ((row >> 2) << 4));
                *(__hip_bfloat16*)(GsB + goff) = __float2bfloat16(v);
            }
        }
        // (5) GEMM2: Out[16 x 288] += P[16 x 32] * DtB; swizzled reads (per-wave
        //     Gs RAW ordered by compiler lgkmcnt, R8-verified pattern)
        bf16x8 a2 = *(const bf16x8*)(GsB + gA);
        #pragma unroll
        for (int nf = 0; nf < 18; ++nf) {
            bf16x8 b2 = *(const bf16x8*)(DtB + nf * 1024 + cA);
            acc[nf] = __builtin_amdgcn_mfma_f32_16x16x32_bf16(a2, b2, acc[nf], 0, 0, 0);
        }
        // protect DsB/DtB/GsB before next iteration's convert overwrites them
        __builtin_amdgcn_s_barrier();
    }
    #undef STAGE

    // epilogue: R8-identical part layout.  wave w == R8's (wave=w>>1, h=w&1):
    // elem ((h*9+m)*64 + lane)*8 + j  <=>  acc[2m + (j>>2)][j&3]
    int h = wave & 1;
    __hip_bfloat16* pw = part + (size_t)bx * (NBATCH * DIMP)
                       + (size_t)(wave >> 1) * 32 * DIMP;
    #pragma unroll
    for (int m = 0; m < 9; ++m) {
        __hip_bfloat16 o8[8];
        #pragma unroll
        for (int j = 0; j < 8; ++j)
            o8[j] = __float2bfloat16(acc[2 * m + (j >> 2)][j & 3]);
        *(bf16x8*)(pw + (size_t)((h * 9 + m) * 64 + lane) * 8) = *(const bf16x8*)o8;
    }
}

// ---------- reduce permuted bf16 partials over 256 z-chunks: 576 blocks x 16 slots
__global__ void k_reduce(const __hip_bfloat16* __restrict__ part, float* __restrict__ out) {
    __shared__ float red[3][16][8];
    int t = threadIdx.x, wave = t >> 6, lane = t & 63;
    int j = lane & 15;                 // slot within block
    int zg = wave * 4 + (lane >> 4);   // 0..15 zc-group
    int s = blockIdx.x * 16 + j;       // 576*16 = 9216 b128 slots per chunk
    const __hip_bfloat16* p = part + (size_t)s * 8;
    float sum[8];
    #pragma unroll
    for (int kk = 0; kk < 8; ++kk) sum[kk] = 0.f;
    #pragma unroll 4
    for (int ii = 0; ii < 16; ++ii) {
        bf16x8 v = *(const bf16x8*)(p + (size_t)(zg * 16 + ii) * (NBATCH * DIMP));
        #pragma unroll
        for (int kk = 0; kk < 8; ++kk) {
            __hip_bfloat16 h; *(short*)&h = v[kk];
            sum[kk] += __bfloat162float(h);
        }
    }
    #pragma unroll
    for (int kk = 0; kk < 8; ++kk) {
        sum[kk] += __shfl_down(sum[kk], 16);
        sum[kk] += __shfl_down(sum[kk], 32);
    }
    if (wave > 0 && lane < 16) {
        #pragma unroll
        for (int kk = 0; kk < 8; ++kk) red[wave - 1][lane][kk] = sum[kk];
    }
    __syncthreads();
    if (wave == 0 && lane < 16) {
        #pragma unroll
        for (int w = 0; w < 3; ++w)
            #pragma unroll
            for (int kk = 0; kk < 8; ++kk) sum[kk] += red[w][lane][kk];
        int wr = s / 1152, si = s % 1152;
        int lane_m = si % 64, m9 = si / 64;
        int h = m9 / 9, m = m9 % 9, q = lane_m >> 4, ln = lane_m & 15;
        int rowb = wr * 32 + h * 16 + q * 4;
        #pragma unroll
        for (int j8 = 0; j8 < 8; ++j8) {
            int nf = 2 * m + (j8 >> 2), r = j8 & 3;
            int i = nf * 16 + ln;
            if (i < DIM) out[(rowb + r) * DIM + i] = sum[j8];
        }
    }
}

extern "C" void kernel_launch(void* const* d_in, const int* in_sizes, int n_in,
                              void* d_out, int out_size, void* d_ws, size_t ws_size,
                              hipStream_t stream) {
    const float* F  = (const float*)d_in[0];
    const float* D  = (const float*)d_in[1];
    const float* qw = (const float*)d_in[2];
    char* ws = (char*)d_ws;
    __hip_bfloat16* part = (__hip_bfloat16*)(ws + WS_PART);

    k_main<<<NCHUNK, 1024, 0, stream>>>(F, D, qw, part);
    k_reduce<<<576, 256, 0, stream>>>(part, (float*)d_out);
}

// Round 16
// 136.152 us; speedup vs baseline: 1.3120x; 1.3120x over previous
//
#include <hip/hip_runtime.h>
#include <hip/hip_bf16.h>

#define DIM    286
#define DIMP   288
#define NBATCH 256
#define NB_    24
#define NA_    48
#define ZC     32        // z per tile
#define NTILES 1728      // 55296/32
#define NCHUNK 256       // k_main grid.x; 192 blocks x 7 tiles + 64 x 6
#define S_CONST 16.911534525287763f
#define INV_S   0.05913123959890826f
#define ACT_CST 1.5927f  // normalize2mom const for tanh
#define TWO_LOG2E 2.8853900817779268f   // 2*log2(e): expf(-2a) == exp2(-TWO_LOG2E*a)

typedef short bf16x8 __attribute__((ext_vector_type(8)));
typedef float f32x4  __attribute__((ext_vector_type(4)));

// ws layout (bytes)
#define WS_FBF  0u                            // Fbf: 256*288*2 = 147456
#define WS_PART 147456u                       // part: 256*256*288*2 = 37748736

typedef const __attribute__((address_space(1))) char GA;
typedef __attribute__((address_space(3))) char LA;
__device__ __forceinline__ void gload_lds16(const void* g, void* l) {
    __builtin_amdgcn_global_load_lds((GA*)g, (LA*)l, 16, 0, 0);
}

// ---------- tiny prep: F -> bf16 [256][288] scaled by 1/s (288 blocks x 256 thr)
__global__ void k_prepF(const float* __restrict__ F, __hip_bfloat16* __restrict__ Fbf) {
    int o = blockIdx.x * 256 + threadIdx.x;   // 288*256 == 73728 exactly
    int row = o / DIMP, col = o % DIMP;
    float v = (col < DIM) ? F[row * DIM + col] * INV_S : 0.f;
    Fbf[o] = __float2bfloat16(v);
}

// ---------- fused main (R8 champion + two counter-driven fixes):
// (1) Ds-convert task remap d = lane*72 + wave*9 + m:  z = lane>>1 (32 distinct
//     z per wave -> Ds writes spread across all banks; was 4-way conflict with
//     all lanes sharing one z), and the div/wrap walk becomes a pure increment.
//     Bijective; byte-identical Ds contents.
// (2) s_setprio(1) around the MFMA clusters (T5: phase-split waves -> scheduler
//     can favor MFMA-entering waves).
// REGISTER LAW (r0..r15, final): 512-thr/2-waves => ~128 arch-VGPR cap + AGPR
// acc; acc(144) forbids ANY cross-phase register cache.  A streams from L2.
__launch_bounds__(512, 2)
__global__ void k_main(const __hip_bfloat16* __restrict__ Fbf,
                       const float* __restrict__ D,
                       const float* __restrict__ qw,
                       __hip_bfloat16* __restrict__ part) {
    __shared__ __align__(16) float Traw[2][9216];  // raw f32 tile dbuf: 73728 B
    __shared__ __align__(16) char DsB[18432];      // bf16 [ks][z][i32], hash ((z&7)<<4)
    __shared__ __align__(16) char DtB[18432];      // bf16 [i][z],      hash ((i&7)<<4)
    __shared__ __align__(16) char GsB[16384];      // per-wave 2KB G,   hash ((row>>2)<<4)
    __shared__ float qs[24];

    int t = threadIdx.x;
    int wave = t >> 6, lane = t & 63, ln = lane & 15, q = lane >> 4;
    int cA = (ln * 64 + q * 16) ^ ((ln & 7) << 4);
    int rq = ln * 64 + q * 16;
    int gA0 = (wave << 11) + (rq ^ ((ln >> 2) << 4));
    int gA1 = (wave << 11) + 1024 + (rq ^ ((4 + (ln >> 2)) << 4));

    if (t < 24) qs[t] = qw[t] * S_CONST;

    int rowbase = wave * 32;
    // A-frags stream from L2-resident Fbf (tile-invariant; NOT register-cached)
    const __hip_bfloat16* fp0 = Fbf + (size_t)(rowbase + ln) * DIMP + q * 8;
    const __hip_bfloat16* fp1 = fp0 + 16 * DIMP;

    f32x4 acc[2][18];
    #pragma unroll
    for (int h = 0; h < 2; ++h)
        #pragma unroll
        for (int n = 0; n < 18; ++n) acc[h][n] = (f32x4){0.f, 0.f, 0.f, 0.f};

    int bx = blockIdx.x;
    int tstart = (bx < 192) ? bx * 7 : bx * 6 + 192;   // 192*7 + 64*6 = 1728
    int ntile = (bx < 192) ? 7 : 6;

    // Ds-convert remap: z const per lane, i walks +2 per m (no div, no wrap)
    int zconv = lane >> 1;                       // 0..31
    int iconv0 = (lane & 1) * 144 + wave * 18;   // i = iconv0 + 2m, m=0..8
    int dsbase = ((zconv * 64) ^ ((zconv & 7) << 4));   // row part of Ds offset

    // DMA one raw f32 tile (36608 B = 35 full 1KB chunks + 768B tail):
    // waves 0-3 issue 5 chunks, waves 4-7 issue 4
    #define STAGE(TI, BUF) do {                                                    \
        const char* _s = (const char*)(D + (size_t)(tstart + (TI)) * 9152);        \
        char* _d = (char*)Traw[BUF];                                               \
        _Pragma("unroll")                                                          \
        for (int _j = 0; _j < 5; ++_j) {                                           \
            int _c = wave + _j * 8;                                                \
            if (_c < 35 || (_c == 35 && lane < 48))                                \
                gload_lds16(_s + _c * 1024 + lane * 16, _d + _c * 1024);           \
        }                                                                          \
    } while (0)

    STAGE(0, 0);
    STAGE(1, 1);   // ntile >= 6 always
    asm volatile("s_waitcnt lgkmcnt(0)" ::: "memory");   // qs store drained pre-barrier

    #pragma unroll 1
    for (int k = 0; k < ntile; ++k) {
        // (1) tile-k batch landed; leave tile-(k+1) batch in flight
        if (k + 1 < ntile) {
            if (wave < 4) asm volatile("s_waitcnt vmcnt(5)" ::: "memory");
            else          asm volatile("s_waitcnt vmcnt(4)" ::: "memory");
        } else {
            asm volatile("s_waitcnt vmcnt(0)" ::: "memory");
        }
        __builtin_amdgcn_s_barrier();

        // (2) convert Traw[k&1] -> DsB + DtB.
        //     Ds: remapped tasks -- lane-local z, conflict-free spread writes.
        //     DtB is a PURE bf16 transpose of D (qw folded into act below).
        const float* T = Traw[k & 1];
        {
            const float* Tz = T + zconv * DIM;
            #pragma unroll
            for (int m = 0; m < 9; ++m) {
                int i = iconv0 + 2 * m;
                __hip_bfloat162 o2;
                if (i < DIM) {
                    float2 v = *(const float2*)(Tz + i);             // 8B aligned
                    o2.x = __float2bfloat16(v.x); o2.y = __float2bfloat16(v.y);
                } else {
                    o2.x = __float2bfloat16(0.f); o2.y = o2.x;       // pad 286..287
                }
                int off = ((i >> 5) * 2048) + (dsbase ^ ((i & 31) * 2));
                *(__hip_bfloat162*)(DsB + off) = o2;
            }
        }
        #pragma unroll
        for (int s5 = 0; s5 < 3; ++s5) {
            int idx = t + s5 * 512;
            if (idx < 1152) {
                int i = idx >> 2, zc = idx & 3;
                __hip_bfloat16 o8[8];
                #pragma unroll
                for (int j = 0; j < 8; ++j)
                    o8[j] = __float2bfloat16(T[(zc * 8 + j) * DIM + i]);
                int off = (i * 64 + zc * 16) ^ ((i & 7) << 4);
                *(bf16x8*)(DtB + off) = *(const bf16x8*)o8;
            }
        }
        asm volatile("s_waitcnt lgkmcnt(0)" ::: "memory");
        __builtin_amdgcn_s_barrier();

        // (3) issue tile k+2 DMA into the Traw buffer convert just finished reading
        if (k + 2 < ntile) STAGE(k + 2, k & 1);

        // per-lane quadrature scale: qv(z) = qs[(z/48)%24], z = z0t + zh*16 + ln
        int z0t = (tstart + k) * 32;
        float qv0 = qs[((z0t + ln) / 48) % 24];
        float qv1 = qs[((z0t + 16 + ln) / 48) % 24];

        // (4) GEMM1: G[32 x 32] per wave, K=288; A streamed from L2 (unroll 3),
        //     B swizzled conflict-free b128 LDS reads.  setprio around MFMAs.
        f32x4 g00 = (f32x4){0.f,0.f,0.f,0.f}, g01 = (f32x4){0.f,0.f,0.f,0.f};
        f32x4 g10 = (f32x4){0.f,0.f,0.f,0.f}, g11 = (f32x4){0.f,0.f,0.f,0.f};
        __builtin_amdgcn_s_setprio(1);
        #pragma unroll 3
        for (int ks = 0; ks < 9; ++ks) {
            bf16x8 a0 = *(const bf16x8*)(fp0 + ks * 32);
            bf16x8 a1 = *(const bf16x8*)(fp1 + ks * 32);
            bf16x8 b0 = *(const bf16x8*)(DsB + ks * 2048 + cA);
            bf16x8 b1 = *(const bf16x8*)(DsB + ks * 2048 + 1024 + cA);
            g00 = __builtin_amdgcn_mfma_f32_16x16x32_bf16(a0, b0, g00, 0, 0, 0);
            g01 = __builtin_amdgcn_mfma_f32_16x16x32_bf16(a0, b1, g01, 0, 0, 0);
            g10 = __builtin_amdgcn_mfma_f32_16x16x32_bf16(a1, b0, g10, 0, 0, 0);
            g11 = __builtin_amdgcn_mfma_f32_16x16x32_bf16(a1, b1, g11, 0, 0, 0);
        }
        __builtin_amdgcn_s_setprio(0);
        // act = qv * ACT_CST*tanh(g): tanh(a) = 1 - 2e/(1+e), e = 2^(-2*log2e*a)
        #pragma unroll
        for (int h = 0; h < 2; ++h) {
            #pragma unroll
            for (int zh = 0; zh < 2; ++zh) {
                f32x4 g = (h == 0) ? (zh == 0 ? g00 : g01) : (zh == 0 ? g10 : g11);
                float qv = (zh == 0) ? qv0 : qv1;
                #pragma unroll
                for (int r = 0; r < 4; ++r) {
                    float x = g[r];
                    float a = fabsf(x);
                    float e = __builtin_amdgcn_exp2f(-TWO_LOG2E * a);
                    float v = ACT_CST - 2.f * ACT_CST * e * __builtin_amdgcn_rcpf(1.f + e);
                    v = copysignf(v, x) * qv;
                    int row = h * 16 + q * 4 + r;              // row>>2 = h*4+q
                    int goff = (wave << 11)
                             + ((row * 64 + (zh * 16 + ln) * 2) ^ ((row >> 2) << 4));
                    *(__hip_bfloat16*)(GsB + goff) = __float2bfloat16(v);
                }
            }
        }
        // (5) GEMM2: Out[32 x 288] += P[32 x 32] * DtB; swizzled reads
        bf16x8 a20 = *(const bf16x8*)(GsB + gA0);
        bf16x8 a21 = *(const bf16x8*)(GsB + gA1);
        __builtin_amdgcn_s_setprio(1);
        #pragma unroll
        for (int nf = 0; nf < 18; ++nf) {
            bf16x8 b2 = *(const bf16x8*)(DtB + nf * 1024 + cA);
            acc[0][nf] = __builtin_amdgcn_mfma_f32_16x16x32_bf16(a20, b2, acc[0][nf], 0, 0, 0);
            acc[1][nf] = __builtin_amdgcn_mfma_f32_16x16x32_bf16(a21, b2, acc[1][nf], 0, 0, 0);
        }
        __builtin_amdgcn_s_setprio(0);
        // protect DsB/DtB/GsB before next iteration's convert overwrites them
        __builtin_amdgcn_s_barrier();
    }
    #undef STAGE

    // epilogue: permuted coalesced layout, 18 b128 stores/thread.
    // elem ((h*9+m)*64 + lane)*8 + j  <=>  acc[h][2m + (j>>2)][j&3]
    __hip_bfloat16* pw = part + (size_t)bx * (NBATCH * DIMP) + (size_t)rowbase * DIMP;
    #pragma unroll
    for (int h = 0; h < 2; ++h) {
        #pragma unroll
        for (int m = 0; m < 9; ++m) {
            __hip_bfloat16 o8[8];
            #pragma unroll
            for (int j = 0; j < 8; ++j)
                o8[j] = __float2bfloat16(acc[h][2 * m + (j >> 2)][j & 3]);
            *(bf16x8*)(pw + (size_t)((h * 9 + m) * 64 + lane) * 8) = *(const bf16x8*)o8;
        }
    }
}

// ---------- reduce permuted bf16 partials over 256 z-chunks: 576 blocks x 16 slots
__global__ void k_reduce(const __hip_bfloat16* __restrict__ part, float* __restrict__ out) {
    __shared__ float red[3][16][8];
    int t = threadIdx.x, wave = t >> 6, lane = t & 63;
    int j = lane & 15;                 // slot within block
    int zg = wave * 4 + (lane >> 4);   // 0..15 zc-group
    int s = blockIdx.x * 16 + j;       // 576*16 = 9216 b128 slots per chunk
    const __hip_bfloat16* p = part + (size_t)s * 8;
    float sum[8];
    #pragma unroll
    for (int kk = 0; kk < 8; ++kk) sum[kk] = 0.f;
    #pragma unroll 4
    for (int ii = 0; ii < 16; ++ii) {
        bf16x8 v = *(const bf16x8*)(p + (size_t)(zg * 16 + ii) * (NBATCH * DIMP));
        #pragma unroll
        for (int kk = 0; kk < 8; ++kk) {
            __hip_bfloat16 h; *(short*)&h = v[kk];
            sum[kk] += __bfloat162float(h);
        }
    }
    #pragma unroll
    for (int kk = 0; kk < 8; ++kk) {
        sum[kk] += __shfl_down(sum[kk], 16);
        sum[kk] += __shfl_down(sum[kk], 32);
    }
    if (wave > 0 && lane < 16) {
        #pragma unroll
        for (int kk = 0; kk < 8; ++kk) red[wave - 1][lane][kk] = sum[kk];
    }
    __syncthreads();
    if (wave == 0 && lane < 16) {
        #pragma unroll
        for (int w = 0; w < 3; ++w)
            #pragma unroll
            for (int kk = 0; kk < 8; ++kk) sum[kk] += red[w][lane][kk];
        int wr = s / 1152, si = s % 1152;
        int lane_m = si % 64, m9 = si / 64;
        int h = m9 / 9, m = m9 % 9, q = lane_m >> 4, ln = lane_m & 15;
        int rowb = wr * 32 + h * 16 + q * 4;
        #pragma unroll
        for (int j8 = 0; j8 < 8; ++j8) {
            int nf = 2 * m + (j8 >> 2), r = j8 & 3;
            int i = nf * 16 + ln;
            if (i < DIM) out[(rowb + r) * DIM + i] = sum[j8];
        }
    }
}

extern "C" void kernel_launch(void* const* d_in, const int* in_sizes, int n_in,
                              void* d_out, int out_size, void* d_ws, size_t ws_size,
                              hipStream_t stream) {
    const float* F  = (const float*)d_in[0];
    const float* D  = (const float*)d_in[1];
    const float* qw = (const float*)d_in[2];
    char* ws = (char*)d_ws;
    __hip_bfloat16* Fbf = (__hip_bfloat16*)(ws + WS_FBF);
    __hip_bfloat16* part = (__hip_bfloat16*)(ws + WS_PART);

    k_prepF<<<288, 256, 0, stream>>>(F, Fbf);
    k_main<<<NCHUNK, 512, 0, stream>>>(Fbf, D, qw, part);
    k_reduce<<<576, 256, 0, stream>>>(part, (float*)d_out);
}